// Round 18
// baseline (1246.488 us; speedup 1.0000x reference)
//
#include <hip/hip_runtime.h>
#include <math.h>

typedef short short8 __attribute__((ext_vector_type(8)));
typedef float f32x4 __attribute__((ext_vector_type(4)));

#define BB 32
#define CIN 256
#define COUT 256
#define SPD 64
#define SPP 4096
#define SDIM 256

constexpr float LIN_SCALE  = 0.0625f;                 // 1/sqrt(256)
constexpr float CONV_SCALE = 0.020833333333333332f;   // 1/sqrt(2304)
constexpr float EPS = 1e-6f;

// ---- ws byte-offset layout ----
#define WSB_STYLE   0ULL
#define WSB_DEMOD   32768ULL
#define WSB_WSQ     65536ULL
#define WSB_SP      327680ULL
#define WSB_DSP     851968ULL
#define WSB_ZERO    852096ULL      // 1 KiB of zeros
#define WSB_WT2     860160ULL      // 1,179,648 B bf16 weights [kc][tap][cog][lane][8]
#define WSB_SSQP    2039808ULL     // 32,768 B ssq partials [256][32] f32
#define WSB_XST     2097152ULL     // 67,108,864 B bf16 xs_t [b][p][ci]
#define WS_NEED     (WSB_XST + 67108864ULL)

__device__ inline unsigned short f2bf(float f) {
    unsigned u = __builtin_bit_cast(unsigned, f);
    u = (u + 0x7fffu + ((u >> 16) & 1u)) >> 16;   // RNE
    return (unsigned short)u;
}

// async global->LDS DMA, 16B per lane; LDS dest = wave-uniform base + lane*16
__device__ inline void dma16(const void* g, void* l) {
    __builtin_amdgcn_global_load_lds(
        (const __attribute__((address_space(1))) unsigned int*)g,
        (__attribute__((address_space(3))) unsigned int*)l, 16, 0, 0);
}

// ---------------- fused prep A: spatial2 + wt4 + wsq + style + zeropad ----
// grid 2848: [0,256) spatial2 | [256,2560) wt4 | [2560,2816) wsq(+zero)
//            | [2816,2848) style (b = bid-2816)
__global__ __launch_bounds__(256) void k_prepA(
    const float* __restrict__ weight,
    const float* __restrict__ style_in,
    const float* __restrict__ sp_w,
    const float* __restrict__ sp_b,
    const float* __restrict__ mod_w,
    const float* __restrict__ mod_b,
    float* __restrict__ wsq,
    unsigned short* __restrict__ wt4,
    float* __restrict__ sp,
    float* __restrict__ ssq_part,
    float* __restrict__ style,
    unsigned* __restrict__ zero)
{
    __shared__ float s_in[32][257];
    __shared__ float sred[256];
    int bid = blockIdx.x, t = threadIdx.x;

    if (bid < 256) {
        // ---- spatial map ----
        int p0 = bid * 16;
        for (int idx = t; idx < 8192; idx += 256) {
            int b = idx >> 8, k = idx & 255;
            s_in[b][k] = style_in[b * 512 + 256 + k];
        }
        __syncthreads();
        int b = t & 31, pl = t >> 5;
        float ss = 0.f;
#pragma unroll
        for (int half = 0; half < 2; half++) {
            int p = p0 + half * 8 + pl;
            const float* wr = sp_w + (size_t)p * 256;
            float a = 0.f;
            for (int k = 0; k < 256; k++) a += s_in[b][k] * wr[k];
            float v = a * LIN_SCALE + sp_b[p];
            sp[b * SPP + p] = v;
            ss += v * v;
        }
        sred[t] = ss;
        __syncthreads();
        if (t < 32) {
            float s = 0.f;
#pragma unroll
            for (int r = 0; r < 8; r++) s += sred[r * 32 + t];
            ssq_part[bid * 32 + t] = s;
        }
    } else if (bid < 2560) {
        // ---- wt4 repack: [kc][tap][cog][lane][8] bf16 ----
        int idx = (bid - 256) * 256 + t;
        int e    = idx & 7;
        int r1   = idx >> 3;
        int lane = r1 & 63;
        int r2   = r1 >> 6;
        int cog  = r2 & 15;
        int r3   = r2 >> 4;       // 0..71
        int tap  = r3 % 9;
        int kc   = r3 / 9;
        int co = cog * 16 + (lane & 15);
        int ci = kc * 32 + (lane >> 4) * 8 + e;
        wt4[idx] = f2bf(weight[(co * 256 + ci) * 9 + tap]);
    } else if (bid < 2816) {
        // ---- wsq (+ zeropad by first block) ----
        int co = bid - 2560, ci = t;
        if (co == 0) zero[ci] = 0u;
        const float* wp = weight + (co * CIN + ci) * 9;
        float s = 0.f;
#pragma unroll
        for (int q = 0; q < 9; q++) { float v = wp[q]; s += v * v; }
        wsq[co * CIN + ci] = s;
    } else {
        // ---- style (EqualLinear), coalesced 4-lane rows ----
        int b = bid - 2816;
        float* s_lin = &s_in[0][0];       // reuse shared
        s_lin[t] = style_in[b * 512 + t];
        __syncthreads();
        int kq = t & 3, rr = t >> 2;
#pragma unroll
        for (int c = 0; c < 4; c++) {
            int ci = c * 64 + rr;
            const float4* wrow = (const float4*)(mod_w + (size_t)ci * 256 + kq * 64);
            float a = 0.f;
#pragma unroll
            for (int j = 0; j < 16; j++) {
                float4 wv = wrow[j];
                int kb = kq * 64 + j * 4;
                a += s_lin[kb] * wv.x + s_lin[kb + 1] * wv.y + s_lin[kb + 2] * wv.z + s_lin[kb + 3] * wv.w;
            }
            a += __shfl_xor(a, 1); a += __shfl_xor(a, 2);
            if (kq == 0) style[b * 256 + ci] = a * LIN_SCALE + mod_b[ci];
        }
    }
}

// ---------------- prep B: demod + dsp -------------------------------------
// grid 33: [0,32) demod (b=bid) | 32 dsp
__global__ __launch_bounds__(256) void k_prepB(
    const float* __restrict__ wsq,
    const float* __restrict__ ssq_part,
    const float* __restrict__ style,
    float* __restrict__ demod,
    float* __restrict__ dsp)
{
    __shared__ float s2[CIN];
    int bid = blockIdx.x, t = threadIdx.x;
    if (bid == 32) {
        if (t < 32) {
            float s = 0.f;
            for (int i = 0; i < 256; i++) s += ssq_part[i * 32 + t];
            dsp[t] = sqrtf((float)SPP / s + EPS);
        }
        return;
    }
    int b = bid;
    float st = style[b * 256 + t];
    s2[t] = st * st;
    __syncthreads();
    int kq = t & 3, rr = t >> 2;
#pragma unroll
    for (int c = 0; c < 4; c++) {
        int co = c * 64 + rr;
        const float4* wrow = (const float4*)(wsq + (size_t)co * 256 + kq * 64);
        float a = 0.f;
#pragma unroll
        for (int j = 0; j < 16; j++) {
            float4 wv = wrow[j];
            int kb = kq * 64 + j * 4;
            a += s2[kb] * wv.x + s2[kb + 1] * wv.y + s2[kb + 2] * wv.z + s2[kb + 3] * wv.w;
        }
        a += __shfl_xor(a, 1); a += __shfl_xor(a, 2);
        if (kq == 0) demod[b * 256 + co] = rsqrtf(CONV_SCALE * CONV_SCALE * a + EPS);
    }
}

// x [b][ci][p] fp32 -> xs_t[b][p][ci] bf16 scaled by style[b][ci].
// float4-vectorized reads (was 64 scalar loads/thread -> 16 float4), LDS
// bf16 tile transpose, packed u32 coalesced writes.
__global__ __launch_bounds__(256) void k_xt(
    const float* __restrict__ x, const float* __restrict__ style,
    unsigned short* __restrict__ xst) {
    __shared__ unsigned short tileb[64][74];   // pq-stride 592B -> 2-way max
    int bid = blockIdx.x;
    int b  = (bid & 7) * 4 + ((bid >> 3) & 3);
    int p0 = (bid >> 5) * 64;
    int t = threadIdx.x;
    int w = t >> 6, lane = t & 63;
    int pq = lane & 15, cg = lane >> 4;
    int hi = t >> 5, lo = t & 31;

    for (int cc = 0; cc < 4; cc++) {
#pragma unroll
        for (int j = 0; j < 4; j++) {
            int ci_l = w * 16 + j * 4 + cg;
            int ci = cc * 64 + ci_l;
            float st = style[b * 256 + ci];
            float4 v = *(const float4*)(x + ((size_t)(b * 256 + ci)) * SPP + p0 + pq * 4);
            tileb[pq * 4 + 0][ci_l] = f2bf(v.x * st);
            tileb[pq * 4 + 1][ci_l] = f2bf(v.y * st);
            tileb[pq * 4 + 2][ci_l] = f2bf(v.z * st);
            tileb[pq * 4 + 3][ci_l] = f2bf(v.w * st);
        }
        __syncthreads();
#pragma unroll
        for (int it = 0; it < 8; it++) {
            int p_l = it * 8 + hi;
            unsigned pk = (unsigned)tileb[p_l][lo * 2]
                        | ((unsigned)tileb[p_l][lo * 2 + 1] << 16);
            unsigned* dst = (unsigned*)xst + ((size_t)(b * SPP + p0 + p_l)) * 128 + cc * 32 + lo;
            *dst = pk;
        }
        __syncthreads();
    }
}

// ---------------- MFMA conv kernel (n=8, 3 blocks/CU) ---------------------
// grid 1024: bid -> [rq(4)][coh(1)][b_lo(2)][xcd(3)], b = xcd*4+b_lo,
// h0 = rq*4. block 256 = 4 waves: cpair=w&1 -> 64-co slab, rpair=w>>1 ->
// rows h0+rpair*2+{0,1}. Wave: 64 co x 128 p, 36 weight loads -> 288 MFMAs.
// launch_bounds(256,3): VGPR cap 170 (uses 128), LDS 51.2KB -> 3 blocks/CU.
__global__ __launch_bounds__(256, 3) void k_conv_mfma(
    const unsigned short* __restrict__ xst,
    const unsigned short* __restrict__ wt4,
    const float* __restrict__ demod,
    const float* __restrict__ sp,
    const float* __restrict__ dsp,
    const unsigned short* __restrict__ zeropad,
    float* __restrict__ out)
{
    __shared__ union {
        char stage[2][25344];      // 2 x 396 slots x 64B (1584 16B-units each)
        float ep[4][2176];         // 4 waves x 32 rows x 68 floats (34816 B)
    } lds;
    __shared__ float demod_l[128];

    int bid = blockIdx.x;
    int xcd  = bid & 7;
    int b_lo = (bid >> 3) & 3;
    int coh  = (bid >> 5) & 1;
    int rq   = bid >> 6;           // 0..15
    int b  = xcd * 4 + b_lo;
    int h0 = rq * 4;
    int t = threadIdx.x;
    int w = t >> 6, lane = t & 63;
    int cpair = w & 1, rpair = w >> 1;
    int cog0 = coh * 8 + cpair * 4;
    int lcol = lane & 15, kg = lane >> 4;

    if (t < 128) demod_l[t] = demod[b * 256 + coh * 128 + t];

    const unsigned short* xb = xst + (size_t)b * SPP * 256;

    // per-thread DMA source pointers (kc advances source by 32 elements)
    const unsigned short* sbase[7];
#pragma unroll
    for (int it = 0; it < 7; it++) {
        int idx16 = t + it * 256;
        const unsigned short* s = zeropad;
        if (idx16 < 1584) {
            int slot = idx16 >> 2, j = idx16 & 3;
            int row = slot / 66, col = slot - row * 66;   // row 0..5
            int g = j ^ ((slot >> 1) & 3);     // inverse swizzle on source
            int gh = h0 + row - 1, gw = col - 1;
            if ((unsigned)gh < 64u && (unsigned)gw < 64u)
                s = xb + ((size_t)(gh * 64 + gw)) * 256 + g * 8;
        }
        sbase[it] = s;
    }

#define STAGE_DMA(BUF, KC) { _Pragma("unroll") \
    for (int it = 0; it < 6; it++) \
        dma16(sbase[it] + (KC) * 32, &lds.stage[BUF][0] + (t + it * 256) * 16); \
    if (t < 48) dma16(sbase[6] + (KC) * 32, &lds.stage[BUF][0] + (t + 1536) * 16); }

    STAGE_DMA(0, 0);

    f32x4 acc[4][8];
#pragma unroll
    for (int m = 0; m < 4; m++)
#pragma unroll
        for (int n = 0; n < 8; n++) acc[m][n] = (f32x4){0.f, 0.f, 0.f, 0.f};

    asm volatile("s_waitcnt vmcnt(0) lgkmcnt(0)" ::: "memory");
    __builtin_amdgcn_s_barrier();

#define LOADW(a0,a1,a2,a3, TAP) { \
        const unsigned short* wp_ = wkc + (size_t)(((TAP) * 16 + cog0)) * 512 + lane * 8; \
        a0 = *(const short8*)(wp_); \
        a1 = *(const short8*)(wp_ + 512); \
        a2 = *(const short8*)(wp_ + 1024); \
        a3 = *(const short8*)(wp_ + 1536); }

#define LOADB(a0,a1,a2,a3, TAP, HALF) { \
        const int dh_ = (TAP) / 3, dw_ = (TAP) - 3 * (dh_); \
        int s0_ = (rpair * 2 + (HALF) + dh_) * 66 + dw_ + lcol; \
        int q_ = (s0_ >> 1) & 3; \
        const char* lbp_ = lb + s0_ * 64 + ((kg ^ q_) << 4); \
        a0 = *(const short8*)(lbp_); \
        a1 = *(const short8*)(lbp_ + 1024); \
        a2 = *(const short8*)(lbp_ + 2048); \
        a3 = *(const short8*)(lbp_ + 3072); }

#define BURSTN(w0_,w1_,w2_,w3_, x0_,x1_,x2_,x3_, NO) { \
        __builtin_amdgcn_s_setprio(1); \
        acc[0][NO+0] = __builtin_amdgcn_mfma_f32_16x16x32_bf16(w0_, x0_, acc[0][NO+0], 0, 0, 0); \
        acc[1][NO+0] = __builtin_amdgcn_mfma_f32_16x16x32_bf16(w1_, x0_, acc[1][NO+0], 0, 0, 0); \
        acc[2][NO+0] = __builtin_amdgcn_mfma_f32_16x16x32_bf16(w2_, x0_, acc[2][NO+0], 0, 0, 0); \
        acc[3][NO+0] = __builtin_amdgcn_mfma_f32_16x16x32_bf16(w3_, x0_, acc[3][NO+0], 0, 0, 0); \
        acc[0][NO+1] = __builtin_amdgcn_mfma_f32_16x16x32_bf16(w0_, x1_, acc[0][NO+1], 0, 0, 0); \
        acc[1][NO+1] = __builtin_amdgcn_mfma_f32_16x16x32_bf16(w1_, x1_, acc[1][NO+1], 0, 0, 0); \
        acc[2][NO+1] = __builtin_amdgcn_mfma_f32_16x16x32_bf16(w2_, x1_, acc[2][NO+1], 0, 0, 0); \
        acc[3][NO+1] = __builtin_amdgcn_mfma_f32_16x16x32_bf16(w3_, x1_, acc[3][NO+1], 0, 0, 0); \
        acc[0][NO+2] = __builtin_amdgcn_mfma_f32_16x16x32_bf16(w0_, x2_, acc[0][NO+2], 0, 0, 0); \
        acc[1][NO+2] = __builtin_amdgcn_mfma_f32_16x16x32_bf16(w1_, x2_, acc[1][NO+2], 0, 0, 0); \
        acc[2][NO+2] = __builtin_amdgcn_mfma_f32_16x16x32_bf16(w2_, x2_, acc[2][NO+2], 0, 0, 0); \
        acc[3][NO+2] = __builtin_amdgcn_mfma_f32_16x16x32_bf16(w3_, x2_, acc[3][NO+2], 0, 0, 0); \
        acc[0][NO+3] = __builtin_amdgcn_mfma_f32_16x16x32_bf16(w0_, x3_, acc[0][NO+3], 0, 0, 0); \
        acc[1][NO+3] = __builtin_amdgcn_mfma_f32_16x16x32_bf16(w1_, x3_, acc[1][NO+3], 0, 0, 0); \
        acc[2][NO+3] = __builtin_amdgcn_mfma_f32_16x16x32_bf16(w2_, x3_, acc[2][NO+3], 0, 0, 0); \
        acc[3][NO+3] = __builtin_amdgcn_mfma_f32_16x16x32_bf16(w3_, x3_, acc[3][NO+3], 0, 0, 0); \
        __builtin_amdgcn_s_setprio(0); }

    int cur = 0;
    for (int kc = 0; kc < 8; kc++) {
        const char* lb = &lds.stage[cur][0];
        const unsigned short* wkc = wt4 + (size_t)(kc * 9) * 8192;

        short8 wc0, wc1, wc2, wc3, wn0, wn1, wn2, wn3;
        short8 b00, b01, b02, b03, b0n0, b0n1, b0n2, b0n3;
        short8 b10, b11, b12, b13;
        // A(0), B(0,h0), A(1) issued FIRST (oldest in vmcnt queue), DMA after
        LOADW(wc0, wc1, wc2, wc3, 0);
        LOADB(b00, b01, b02, b03, 0, 0);
        LOADW(wn0, wn1, wn2, wn3, 1);
        if (kc < 7) STAGE_DMA(cur ^ 1, kc + 1);

#pragma unroll
        for (int tap = 0; tap < 9; tap++) {
            if (tap >= 1 && tap < 8) {
                switch (tap + 1) {   // A(tap+1); tap0's A(1) preloaded
                    case 2: LOADW(wn0,wn1,wn2,wn3,2); break;
                    case 3: LOADW(wn0,wn1,wn2,wn3,3); break;
                    case 4: LOADW(wn0,wn1,wn2,wn3,4); break;
                    case 5: LOADW(wn0,wn1,wn2,wn3,5); break;
                    case 6: LOADW(wn0,wn1,wn2,wn3,6); break;
                    case 7: LOADW(wn0,wn1,wn2,wn3,7); break;
                    case 8: LOADW(wn0,wn1,wn2,wn3,8); break;
                }
            }
            switch (tap) {           // B(tap, h1), consumed by BURST half1
                case 0: LOADB(b10,b11,b12,b13,0,1); break;
                case 1: LOADB(b10,b11,b12,b13,1,1); break;
                case 2: LOADB(b10,b11,b12,b13,2,1); break;
                case 3: LOADB(b10,b11,b12,b13,3,1); break;
                case 4: LOADB(b10,b11,b12,b13,4,1); break;
                case 5: LOADB(b10,b11,b12,b13,5,1); break;
                case 6: LOADB(b10,b11,b12,b13,6,1); break;
                case 7: LOADB(b10,b11,b12,b13,7,1); break;
                case 8: LOADB(b10,b11,b12,b13,8,1); break;
            }
            BURSTN(wc0, wc1, wc2, wc3, b00, b01, b02, b03, 0);   // half0
            if (tap < 8) {
                switch (tap + 1) {   // B(tap+1, h0)
                    case 1: LOADB(b0n0,b0n1,b0n2,b0n3,1,0); break;
                    case 2: LOADB(b0n0,b0n1,b0n2,b0n3,2,0); break;
                    case 3: LOADB(b0n0,b0n1,b0n2,b0n3,3,0); break;
                    case 4: LOADB(b0n0,b0n1,b0n2,b0n3,4,0); break;
                    case 5: LOADB(b0n0,b0n1,b0n2,b0n3,5,0); break;
                    case 6: LOADB(b0n0,b0n1,b0n2,b0n3,6,0); break;
                    case 7: LOADB(b0n0,b0n1,b0n2,b0n3,7,0); break;
                    case 8: LOADB(b0n0,b0n1,b0n2,b0n3,8,0); break;
                }
            }
            BURSTN(wc0, wc1, wc2, wc3, b10, b11, b12, b13, 4);   // half1
            wc0 = wn0; wc1 = wn1; wc2 = wn2; wc3 = wn3;
            b00 = b0n0; b01 = b0n1; b02 = b0n2; b03 = b0n3;
        }

        asm volatile("s_waitcnt vmcnt(0) lgkmcnt(0)" ::: "memory");
        __builtin_amdgcn_s_barrier();
        cur ^= 1;
    }

    // ---- epilogue: scale, per-wave LDS transpose, coalesced dwordx4 stores ----
    float dspb = dsp[b];
    float spn[2][4];
#pragma unroll
    for (int half = 0; half < 2; half++) {
        int hout = h0 + rpair * 2 + half;
#pragma unroll
        for (int nn = 0; nn < 4; nn++)
            spn[half][nn] = sp[b * SPP + hout * 64 + nn * 16 + lcol] * dspb;
    }

    float* ep = &lds.ep[w][0];
#pragma unroll
    for (int half = 0; half < 2; half++) {
        int hout = h0 + rpair * 2 + half;
#pragma unroll
        for (int ch = 0; ch < 2; ch++) {          // 2 chunks of 32 co
#pragma unroll
            for (int mm = 0; mm < 2; mm++) {
#pragma unroll
                for (int r2 = 0; r2 < 4; r2++) {
                    int lr = mm * 16 + kg * 4 + r2;
                    float dm = demod_l[cpair * 64 + ch * 32 + lr] * CONV_SCALE;
#pragma unroll
                    for (int nn = 0; nn < 4; nn++)
                        ep[lr * 68 + nn * 16 + lcol] =
                            acc[ch * 2 + mm][half * 4 + nn][r2] * dm * spn[half][nn];
                }
            }
#pragma unroll
            for (int i = 0; i < 8; i++) {
                int lr = i * 4 + kg;
                f32x4 v = *(const f32x4*)(ep + lr * 68 + lcol * 4);
                int co_g = coh * 128 + cpair * 64 + ch * 32 + lr;
                *(f32x4*)&out[((size_t)(b * 256 + co_g)) * SPP + hout * 64 + lcol * 4] = v;
            }
        }
    }
}

// ---------------- fallback-path kernels (round-1 known-good) --------------

__global__ void k_wsq(const float* __restrict__ weight, float* __restrict__ wsq,
                      unsigned* __restrict__ zero) {
    int co = blockIdx.x, ci = threadIdx.x;
    if (co == 0) zero[ci] = 0u;
    const float* wp = weight + (co * CIN + ci) * 9;
    float s = 0.f;
#pragma unroll
    for (int t = 0; t < 9; t++) { float v = wp[t]; s += v * v; }
    wsq[co * CIN + ci] = s;
}

__global__ void k_style_fb(const float* __restrict__ style_in,
                           const float* __restrict__ mod_w,
                           const float* __restrict__ mod_b,
                           const float* __restrict__ wsq,
                           float* __restrict__ style,
                           float* __restrict__ demod) {
    __shared__ float s_in[SDIM];
    __shared__ float s2[CIN];
    int b = blockIdx.x, t = threadIdx.x;
    s_in[t] = style_in[b * 512 + t];
    __syncthreads();
    const float* mw = mod_w + t * SDIM;
    float acc = 0.f;
    for (int k = 0; k < SDIM; k++) acc += s_in[k] * mw[k];
    float st = acc * LIN_SCALE + mod_b[t];
    style[b * CIN + t] = st;
    s2[t] = st * st;
    __syncthreads();
    const float* wq = wsq + t * CIN;
    float d = 0.f;
    for (int ci = 0; ci < CIN; ci++) d += wq[ci] * s2[ci];
    demod[b * COUT + t] = rsqrtf(CONV_SCALE * CONV_SCALE * d + EPS);
}

__global__ void k_spatial(const float* __restrict__ style_in,
                          const float* __restrict__ sp_w,
                          const float* __restrict__ sp_b,
                          float* __restrict__ sp,
                          float* __restrict__ dsp) {
    __shared__ float s_in[SDIM];
    __shared__ float red[256];
    int b = blockIdx.x, t = threadIdx.x;
    s_in[t] = style_in[b * 512 + 256 + t];
    __syncthreads();
    float ss = 0.f;
    for (int i = 0; i < 16; i++) {
        int p = i * 256 + t;
        const float* wr = sp_w + p * SDIM;
        float acc = 0.f;
        for (int k = 0; k < SDIM; k++) acc += s_in[k] * wr[k];
        float v = acc * LIN_SCALE + sp_b[p];
        sp[b * SPP + p] = v;
        ss += v * v;
    }
    red[t] = ss; __syncthreads();
    for (int o = 128; o > 0; o >>= 1) { if (t < o) red[t] += red[t + o]; __syncthreads(); }
    if (t == 0) dsp[b] = sqrtf((float)SPP / red[0] + EPS);
}

#define COTILE 16
#define TS 32
#define HALO 34
#define XS 36

__global__ __launch_bounds__(256) void k_conv_f32(
    const float* __restrict__ x, const float* __restrict__ weight,
    const float* __restrict__ style, const float* __restrict__ demod,
    const float* __restrict__ sp, const float* __restrict__ dsp,
    float* __restrict__ out) {
    __shared__ float xt[HALO * XS];
    __shared__ float wl[COTILE * 12];
    __shared__ float dml[COTILE];

    int bid = blockIdx.x;
    int tile = bid & 3;
    int cot = (bid >> 2) & 15;
    int b = bid >> 6;
    int h0 = (tile >> 1) * TS, w0 = (tile & 1) * TS;
    int t = threadIdx.x;
    int r = t >> 3;
    int cb = (t & 7) * 4;

    if (t < COTILE) dml[t] = demod[b * COUT + cot * COTILE + t];

    float acc[COTILE][4];
#pragma unroll
    for (int co = 0; co < COTILE; co++)
#pragma unroll
        for (int c = 0; c < 4; c++) acc[co][c] = 0.f;

    const float* xb = x + (size_t)b * CIN * SPP;
    const float* stb = style + b * CIN;

    for (int ci = 0; ci < CIN; ci++) {
        __syncthreads();
        const float* xc = xb + ci * SPP;
        for (int idx = t; idx < HALO * HALO; idx += 256) {
            int i = idx / HALO, j = idx - i * HALO;
            int h = h0 + i - 1, wv2 = w0 + j - 1;
            float v = 0.f;
            if ((unsigned)h < SPD && (unsigned)wv2 < SPD) v = xc[h * SPD + wv2];
            xt[i * XS + j] = v;
        }
        if (t < COTILE * 9) {
            int co = t / 9, tap = t - co * 9;
            float wv = weight[((cot * COTILE + co) * CIN + ci) * 9 + tap];
            wl[co * 12 + tap] = wv * (CONV_SCALE * stb[ci]) * dml[co];
        }
        __syncthreads();

        float xv[3][6];
#pragma unroll
        for (int dh = 0; dh < 3; dh++)
#pragma unroll
            for (int jj = 0; jj < 6; jj++)
                xv[dh][jj] = xt[(r + dh) * XS + cb + jj];

#pragma unroll
        for (int co = 0; co < COTILE; co++) {
            float w9[9];
#pragma unroll
            for (int q = 0; q < 9; q++) w9[q] = wl[co * 12 + q];
#pragma unroll
            for (int c = 0; c < 4; c++) {
                float a = acc[co][c];
#pragma unroll
                for (int dh = 0; dh < 3; dh++)
#pragma unroll
                    for (int dw = 0; dw < 3; dw++)
                        a += w9[dh * 3 + dw] * xv[dh][c + dw];
                acc[co][c] = a;
            }
        }
    }

    float dspb = dsp[b];
    int hh = h0 + r, ww = w0 + cb;
    const float* spb = sp + b * SPP + hh * SPD + ww;
    float m[4];
#pragma unroll
    for (int c = 0; c < 4; c++) m[c] = spb[c] * dspb;
#pragma unroll
    for (int co = 0; co < COTILE; co++) {
        float4 v = make_float4(acc[co][0] * m[0], acc[co][1] * m[1],
                               acc[co][2] * m[2], acc[co][3] * m[3]);
        *(float4*)&out[(size_t)((b * COUT + cot * COTILE + co) * SPP) + hh * SPD + ww] = v;
    }
}

// ---------------- launcher ----------------

extern "C" void kernel_launch(void* const* d_in, const int* in_sizes, int n_in,
                              void* d_out, int out_size, void* d_ws, size_t ws_size,
                              hipStream_t stream) {
    const float* x        = (const float*)d_in[0];
    const float* style_in = (const float*)d_in[1];
    const float* weight   = (const float*)d_in[2];
    const float* mod_w    = (const float*)d_in[3];
    const float* mod_b    = (const float*)d_in[4];
    const float* sp_w     = (const float*)d_in[5];
    const float* sp_b     = (const float*)d_in[6];
    float* out = (float*)d_out;
    char* wsb = (char*)d_ws;

    float* style = (float*)(wsb + WSB_STYLE);
    float* demod = (float*)(wsb + WSB_DEMOD);
    float* wsq   = (float*)(wsb + WSB_WSQ);
    float* sp    = (float*)(wsb + WSB_SP);
    float* dsp   = (float*)(wsb + WSB_DSP);
    float* ssqp  = (float*)(wsb + WSB_SSQP);
    unsigned short* wt4 = (unsigned short*)(wsb + WSB_WT2);
    unsigned short* xst = (unsigned short*)(wsb + WSB_XST);

    if (ws_size >= WS_NEED) {
        hipLaunchKernelGGL(k_prepA, dim3(2848), dim3(256), 0, stream,
                           weight, style_in, sp_w, sp_b, mod_w, mod_b,
                           wsq, wt4, sp, ssqp, style,
                           (unsigned*)(wsb + WSB_ZERO));
        hipLaunchKernelGGL(k_xt, dim3(2048), dim3(256), 0, stream, x, style, xst);
        hipLaunchKernelGGL(k_prepB, dim3(33), dim3(256), 0, stream,
                           wsq, ssqp, style, demod, dsp);
        hipLaunchKernelGGL(k_conv_mfma, dim3(1024), dim3(256), 0, stream,
                           xst, wt4, demod, sp, dsp,
                           (const unsigned short*)(wsb + WSB_ZERO), out);
    } else {
        hipLaunchKernelGGL(k_wsq, dim3(COUT), dim3(CIN), 0, stream,
                           weight, wsq, (unsigned*)(wsb + WSB_ZERO));
        hipLaunchKernelGGL(k_style_fb, dim3(BB), dim3(256), 0, stream,
                           style_in, mod_w, mod_b, wsq, style, demod);
        hipLaunchKernelGGL(k_spatial, dim3(BB), dim3(256), 0, stream,
                           style_in, sp_w, sp_b, sp, dsp);
        hipLaunchKernelGGL(k_conv_f32, dim3(2048), dim3(256), 0, stream,
                           x, weight, style, demod, sp, dsp, out);
    }
}

// Round 19
// 210.375 us; speedup vs baseline: 5.9251x; 5.9251x over previous
//
#include <hip/hip_runtime.h>
#include <math.h>

typedef short short8 __attribute__((ext_vector_type(8)));
typedef float f32x4 __attribute__((ext_vector_type(4)));

#define BB 32
#define CIN 256
#define COUT 256
#define SPD 64
#define SPP 4096
#define SDIM 256

constexpr float LIN_SCALE  = 0.0625f;                 // 1/sqrt(256)
constexpr float CONV_SCALE = 0.020833333333333332f;   // 1/sqrt(2304)
constexpr float EPS = 1e-6f;

// ---- ws byte-offset layout ----
#define WSB_STYLE   0ULL
#define WSB_DEMOD   32768ULL
#define WSB_WSQ     65536ULL
#define WSB_SP      327680ULL
#define WSB_DSP     851968ULL
#define WSB_ZERO    852096ULL      // 1 KiB of zeros
#define WSB_WT2     860160ULL      // 1,179,648 B bf16 weights [kc][tap][cog][lane][8]
#define WSB_SSQP    2039808ULL     // 32,768 B ssq partials [256][32] f32
#define WSB_XST     2097152ULL     // 67,108,864 B bf16 xs_t [b][p][ci]
#define WS_NEED     (WSB_XST + 67108864ULL)

__device__ inline unsigned short f2bf(float f) {
    unsigned u = __builtin_bit_cast(unsigned, f);
    u = (u + 0x7fffu + ((u >> 16) & 1u)) >> 16;   // RNE
    return (unsigned short)u;
}

// async global->LDS DMA, 16B per lane; LDS dest = wave-uniform base + lane*16
__device__ inline void dma16(const void* g, void* l) {
    __builtin_amdgcn_global_load_lds(
        (const __attribute__((address_space(1))) unsigned int*)g,
        (__attribute__((address_space(3))) unsigned int*)l, 16, 0, 0);
}

// ---------------- fused prep A: spatial2 + wt4 + wsq + style + zeropad ----
// grid 2848: [0,256) spatial2 | [256,2560) wt4 | [2560,2816) wsq(+zero)
//            | [2816,2848) style (b = bid-2816)
__global__ __launch_bounds__(256) void k_prepA(
    const float* __restrict__ weight,
    const float* __restrict__ style_in,
    const float* __restrict__ sp_w,
    const float* __restrict__ sp_b,
    const float* __restrict__ mod_w,
    const float* __restrict__ mod_b,
    float* __restrict__ wsq,
    unsigned short* __restrict__ wt4,
    float* __restrict__ sp,
    float* __restrict__ ssq_part,
    float* __restrict__ style,
    unsigned* __restrict__ zero)
{
    __shared__ float s_in[32][257];
    __shared__ float sred[256];
    int bid = blockIdx.x, t = threadIdx.x;

    if (bid < 256) {
        // ---- spatial map ----
        int p0 = bid * 16;
        for (int idx = t; idx < 8192; idx += 256) {
            int b = idx >> 8, k = idx & 255;
            s_in[b][k] = style_in[b * 512 + 256 + k];
        }
        __syncthreads();
        int b = t & 31, pl = t >> 5;
        float ss = 0.f;
#pragma unroll
        for (int half = 0; half < 2; half++) {
            int p = p0 + half * 8 + pl;
            const float* wr = sp_w + (size_t)p * 256;
            float a = 0.f;
            for (int k = 0; k < 256; k++) a += s_in[b][k] * wr[k];
            float v = a * LIN_SCALE + sp_b[p];
            sp[b * SPP + p] = v;
            ss += v * v;
        }
        sred[t] = ss;
        __syncthreads();
        if (t < 32) {
            float s = 0.f;
#pragma unroll
            for (int r = 0; r < 8; r++) s += sred[r * 32 + t];
            ssq_part[bid * 32 + t] = s;
        }
    } else if (bid < 2560) {
        // ---- wt4 repack: [kc][tap][cog][lane][8] bf16 ----
        int idx = (bid - 256) * 256 + t;
        int e    = idx & 7;
        int r1   = idx >> 3;
        int lane = r1 & 63;
        int r2   = r1 >> 6;
        int cog  = r2 & 15;
        int r3   = r2 >> 4;       // 0..71
        int tap  = r3 % 9;
        int kc   = r3 / 9;
        int co = cog * 16 + (lane & 15);
        int ci = kc * 32 + (lane >> 4) * 8 + e;
        wt4[idx] = f2bf(weight[(co * 256 + ci) * 9 + tap]);
    } else if (bid < 2816) {
        // ---- wsq (+ zeropad by first block) ----
        int co = bid - 2560, ci = t;
        if (co == 0) zero[ci] = 0u;
        const float* wp = weight + (co * CIN + ci) * 9;
        float s = 0.f;
#pragma unroll
        for (int q = 0; q < 9; q++) { float v = wp[q]; s += v * v; }
        wsq[co * CIN + ci] = s;
    } else {
        // ---- style (EqualLinear), coalesced 4-lane rows ----
        int b = bid - 2816;
        float* s_lin = &s_in[0][0];       // reuse shared
        s_lin[t] = style_in[b * 512 + t];
        __syncthreads();
        int kq = t & 3, rr = t >> 2;
#pragma unroll
        for (int c = 0; c < 4; c++) {
            int ci = c * 64 + rr;
            const float4* wrow = (const float4*)(mod_w + (size_t)ci * 256 + kq * 64);
            float a = 0.f;
#pragma unroll
            for (int j = 0; j < 16; j++) {
                float4 wv = wrow[j];
                int kb = kq * 64 + j * 4;
                a += s_lin[kb] * wv.x + s_lin[kb + 1] * wv.y + s_lin[kb + 2] * wv.z + s_lin[kb + 3] * wv.w;
            }
            a += __shfl_xor(a, 1); a += __shfl_xor(a, 2);
            if (kq == 0) style[b * 256 + ci] = a * LIN_SCALE + mod_b[ci];
        }
    }
}

// ---------------- prep B: demod + dsp -------------------------------------
// grid 33: [0,32) demod (b=bid) | 32 dsp
__global__ __launch_bounds__(256) void k_prepB(
    const float* __restrict__ wsq,
    const float* __restrict__ ssq_part,
    const float* __restrict__ style,
    float* __restrict__ demod,
    float* __restrict__ dsp)
{
    __shared__ float s2[CIN];
    int bid = blockIdx.x, t = threadIdx.x;
    if (bid == 32) {
        if (t < 32) {
            float s = 0.f;
            for (int i = 0; i < 256; i++) s += ssq_part[i * 32 + t];
            dsp[t] = sqrtf((float)SPP / s + EPS);
        }
        return;
    }
    int b = bid;
    float st = style[b * 256 + t];
    s2[t] = st * st;
    __syncthreads();
    int kq = t & 3, rr = t >> 2;
#pragma unroll
    for (int c = 0; c < 4; c++) {
        int co = c * 64 + rr;
        const float4* wrow = (const float4*)(wsq + (size_t)co * 256 + kq * 64);
        float a = 0.f;
#pragma unroll
        for (int j = 0; j < 16; j++) {
            float4 wv = wrow[j];
            int kb = kq * 64 + j * 4;
            a += s2[kb] * wv.x + s2[kb + 1] * wv.y + s2[kb + 2] * wv.z + s2[kb + 3] * wv.w;
        }
        a += __shfl_xor(a, 1); a += __shfl_xor(a, 2);
        if (kq == 0) demod[b * 256 + co] = rsqrtf(CONV_SCALE * CONV_SCALE * a + EPS);
    }
}

// x [b][ci][p] fp32 -> xs_t[b][p][ci] bf16 scaled by style[b][ci].
// float4-vectorized reads, LDS bf16 tile transpose, packed coalesced writes.
__global__ __launch_bounds__(256) void k_xt(
    const float* __restrict__ x, const float* __restrict__ style,
    unsigned short* __restrict__ xst) {
    __shared__ unsigned short tileb[64][74];
    int bid = blockIdx.x;
    int b  = (bid & 7) * 4 + ((bid >> 3) & 3);
    int p0 = (bid >> 5) * 64;
    int t = threadIdx.x;
    int w = t >> 6, lane = t & 63;
    int pq = lane & 15, cg = lane >> 4;
    int hi = t >> 5, lo = t & 31;

    for (int cc = 0; cc < 4; cc++) {
#pragma unroll
        for (int j = 0; j < 4; j++) {
            int ci_l = w * 16 + j * 4 + cg;
            int ci = cc * 64 + ci_l;
            float st = style[b * 256 + ci];
            float4 v = *(const float4*)(x + ((size_t)(b * 256 + ci)) * SPP + p0 + pq * 4);
            tileb[pq * 4 + 0][ci_l] = f2bf(v.x * st);
            tileb[pq * 4 + 1][ci_l] = f2bf(v.y * st);
            tileb[pq * 4 + 2][ci_l] = f2bf(v.z * st);
            tileb[pq * 4 + 3][ci_l] = f2bf(v.w * st);
        }
        __syncthreads();
#pragma unroll
        for (int it = 0; it < 8; it++) {
            int p_l = it * 8 + hi;
            unsigned pk = (unsigned)tileb[p_l][lo * 2]
                        | ((unsigned)tileb[p_l][lo * 2 + 1] << 16);
            unsigned* dst = (unsigned*)xst + ((size_t)(b * SPP + p0 + p_l)) * 128 + cc * 32 + lo;
            *dst = pk;
        }
        __syncthreads();
    }
}

// ---------------- MFMA conv kernel (n=8, launch_bounds(256,2)) ------------
// grid 1024: bid -> [rq(4)][coh(1)][b_lo(2)][xcd(3)], b = xcd*4+b_lo,
// h0 = rq*4. block 256 = 4 waves: cpair=w&1 -> 64-co slab, rpair=w>>1 ->
// rows h0+rpair*2+{0,1}. Wave: 64 co x 128 p, 36 weight loads -> 288 MFMAs.
// NOTE (r18 lesson): unified VGPR/AGPR file -- acc[4][8] = 128 AGPRs counts
// against the per-wave budget. launch_bounds(256,3) caps at ~170 total ->
// the ~110 pipeline regs spill to scratch (2.7GB scratch writes, 7x slower).
// MUST stay at (256,2) = 256-reg cap. r17 measured: 123us, MfmaUtil 57%.
__global__ __launch_bounds__(256, 2) void k_conv_mfma(
    const unsigned short* __restrict__ xst,
    const unsigned short* __restrict__ wt4,
    const float* __restrict__ demod,
    const float* __restrict__ sp,
    const float* __restrict__ dsp,
    const unsigned short* __restrict__ zeropad,
    float* __restrict__ out)
{
    __shared__ union {
        char stage[2][25344];      // 2 x 396 slots x 64B (1584 16B-units each)
        float ep[4][2176];         // 4 waves x 32 rows x 68 floats (34816 B)
    } lds;
    __shared__ float demod_l[128];

    int bid = blockIdx.x;
    int xcd  = bid & 7;
    int b_lo = (bid >> 3) & 3;
    int coh  = (bid >> 5) & 1;
    int rq   = bid >> 6;           // 0..15
    int b  = xcd * 4 + b_lo;
    int h0 = rq * 4;
    int t = threadIdx.x;
    int w = t >> 6, lane = t & 63;
    int cpair = w & 1, rpair = w >> 1;
    int cog0 = coh * 8 + cpair * 4;
    int lcol = lane & 15, kg = lane >> 4;

    if (t < 128) demod_l[t] = demod[b * 256 + coh * 128 + t];

    const unsigned short* xb = xst + (size_t)b * SPP * 256;

    // per-thread DMA source pointers (kc advances source by 32 elements)
    const unsigned short* sbase[7];
#pragma unroll
    for (int it = 0; it < 7; it++) {
        int idx16 = t + it * 256;
        const unsigned short* s = zeropad;
        if (idx16 < 1584) {
            int slot = idx16 >> 2, j = idx16 & 3;
            int row = slot / 66, col = slot - row * 66;   // row 0..5
            int g = j ^ ((slot >> 1) & 3);     // inverse swizzle on source
            int gh = h0 + row - 1, gw = col - 1;
            if ((unsigned)gh < 64u && (unsigned)gw < 64u)
                s = xb + ((size_t)(gh * 64 + gw)) * 256 + g * 8;
        }
        sbase[it] = s;
    }

#define STAGE_DMA(BUF, KC) { _Pragma("unroll") \
    for (int it = 0; it < 6; it++) \
        dma16(sbase[it] + (KC) * 32, &lds.stage[BUF][0] + (t + it * 256) * 16); \
    if (t < 48) dma16(sbase[6] + (KC) * 32, &lds.stage[BUF][0] + (t + 1536) * 16); }

    STAGE_DMA(0, 0);

    f32x4 acc[4][8];
#pragma unroll
    for (int m = 0; m < 4; m++)
#pragma unroll
        for (int n = 0; n < 8; n++) acc[m][n] = (f32x4){0.f, 0.f, 0.f, 0.f};

    asm volatile("s_waitcnt vmcnt(0) lgkmcnt(0)" ::: "memory");
    __builtin_amdgcn_s_barrier();

#define LOADW(a0,a1,a2,a3, TAP) { \
        const unsigned short* wp_ = wkc + (size_t)(((TAP) * 16 + cog0)) * 512 + lane * 8; \
        a0 = *(const short8*)(wp_); \
        a1 = *(const short8*)(wp_ + 512); \
        a2 = *(const short8*)(wp_ + 1024); \
        a3 = *(const short8*)(wp_ + 1536); }

#define LOADB(a0,a1,a2,a3, TAP, HALF) { \
        const int dh_ = (TAP) / 3, dw_ = (TAP) - 3 * (dh_); \
        int s0_ = (rpair * 2 + (HALF) + dh_) * 66 + dw_ + lcol; \
        int q_ = (s0_ >> 1) & 3; \
        const char* lbp_ = lb + s0_ * 64 + ((kg ^ q_) << 4); \
        a0 = *(const short8*)(lbp_); \
        a1 = *(const short8*)(lbp_ + 1024); \
        a2 = *(const short8*)(lbp_ + 2048); \
        a3 = *(const short8*)(lbp_ + 3072); }

#define BURSTN(w0_,w1_,w2_,w3_, x0_,x1_,x2_,x3_, NO) { \
        __builtin_amdgcn_s_setprio(1); \
        acc[0][NO+0] = __builtin_amdgcn_mfma_f32_16x16x32_bf16(w0_, x0_, acc[0][NO+0], 0, 0, 0); \
        acc[1][NO+0] = __builtin_amdgcn_mfma_f32_16x16x32_bf16(w1_, x0_, acc[1][NO+0], 0, 0, 0); \
        acc[2][NO+0] = __builtin_amdgcn_mfma_f32_16x16x32_bf16(w2_, x0_, acc[2][NO+0], 0, 0, 0); \
        acc[3][NO+0] = __builtin_amdgcn_mfma_f32_16x16x32_bf16(w3_, x0_, acc[3][NO+0], 0, 0, 0); \
        acc[0][NO+1] = __builtin_amdgcn_mfma_f32_16x16x32_bf16(w0_, x1_, acc[0][NO+1], 0, 0, 0); \
        acc[1][NO+1] = __builtin_amdgcn_mfma_f32_16x16x32_bf16(w1_, x1_, acc[1][NO+1], 0, 0, 0); \
        acc[2][NO+1] = __builtin_amdgcn_mfma_f32_16x16x32_bf16(w2_, x1_, acc[2][NO+1], 0, 0, 0); \
        acc[3][NO+1] = __builtin_amdgcn_mfma_f32_16x16x32_bf16(w3_, x1_, acc[3][NO+1], 0, 0, 0); \
        acc[0][NO+2] = __builtin_amdgcn_mfma_f32_16x16x32_bf16(w0_, x2_, acc[0][NO+2], 0, 0, 0); \
        acc[1][NO+2] = __builtin_amdgcn_mfma_f32_16x16x32_bf16(w1_, x2_, acc[1][NO+2], 0, 0, 0); \
        acc[2][NO+2] = __builtin_amdgcn_mfma_f32_16x16x32_bf16(w2_, x2_, acc[2][NO+2], 0, 0, 0); \
        acc[3][NO+2] = __builtin_amdgcn_mfma_f32_16x16x32_bf16(w3_, x2_, acc[3][NO+2], 0, 0, 0); \
        acc[0][NO+3] = __builtin_amdgcn_mfma_f32_16x16x32_bf16(w0_, x3_, acc[0][NO+3], 0, 0, 0); \
        acc[1][NO+3] = __builtin_amdgcn_mfma_f32_16x16x32_bf16(w1_, x3_, acc[1][NO+3], 0, 0, 0); \
        acc[2][NO+3] = __builtin_amdgcn_mfma_f32_16x16x32_bf16(w2_, x3_, acc[2][NO+3], 0, 0, 0); \
        acc[3][NO+3] = __builtin_amdgcn_mfma_f32_16x16x32_bf16(w3_, x3_, acc[3][NO+3], 0, 0, 0); \
        __builtin_amdgcn_s_setprio(0); }

    int cur = 0;
    for (int kc = 0; kc < 8; kc++) {
        const char* lb = &lds.stage[cur][0];
        const unsigned short* wkc = wt4 + (size_t)(kc * 9) * 8192;

        short8 wc0, wc1, wc2, wc3, wn0, wn1, wn2, wn3;
        short8 b00, b01, b02, b03, b0n0, b0n1, b0n2, b0n3;
        short8 b10, b11, b12, b13;
        // A(0), B(0,h0), A(1) issued FIRST (oldest in vmcnt queue), DMA after
        LOADW(wc0, wc1, wc2, wc3, 0);
        LOADB(b00, b01, b02, b03, 0, 0);
        LOADW(wn0, wn1, wn2, wn3, 1);
        if (kc < 7) STAGE_DMA(cur ^ 1, kc + 1);

#pragma unroll
        for (int tap = 0; tap < 9; tap++) {
            if (tap >= 1 && tap < 8) {
                switch (tap + 1) {   // A(tap+1); tap0's A(1) preloaded
                    case 2: LOADW(wn0,wn1,wn2,wn3,2); break;
                    case 3: LOADW(wn0,wn1,wn2,wn3,3); break;
                    case 4: LOADW(wn0,wn1,wn2,wn3,4); break;
                    case 5: LOADW(wn0,wn1,wn2,wn3,5); break;
                    case 6: LOADW(wn0,wn1,wn2,wn3,6); break;
                    case 7: LOADW(wn0,wn1,wn2,wn3,7); break;
                    case 8: LOADW(wn0,wn1,wn2,wn3,8); break;
                }
            }
            switch (tap) {           // B(tap, h1), consumed by BURST half1
                case 0: LOADB(b10,b11,b12,b13,0,1); break;
                case 1: LOADB(b10,b11,b12,b13,1,1); break;
                case 2: LOADB(b10,b11,b12,b13,2,1); break;
                case 3: LOADB(b10,b11,b12,b13,3,1); break;
                case 4: LOADB(b10,b11,b12,b13,4,1); break;
                case 5: LOADB(b10,b11,b12,b13,5,1); break;
                case 6: LOADB(b10,b11,b12,b13,6,1); break;
                case 7: LOADB(b10,b11,b12,b13,7,1); break;
                case 8: LOADB(b10,b11,b12,b13,8,1); break;
            }
            BURSTN(wc0, wc1, wc2, wc3, b00, b01, b02, b03, 0);   // half0
            if (tap < 8) {
                switch (tap + 1) {   // B(tap+1, h0)
                    case 1: LOADB(b0n0,b0n1,b0n2,b0n3,1,0); break;
                    case 2: LOADB(b0n0,b0n1,b0n2,b0n3,2,0); break;
                    case 3: LOADB(b0n0,b0n1,b0n2,b0n3,3,0); break;
                    case 4: LOADB(b0n0,b0n1,b0n2,b0n3,4,0); break;
                    case 5: LOADB(b0n0,b0n1,b0n2,b0n3,5,0); break;
                    case 6: LOADB(b0n0,b0n1,b0n2,b0n3,6,0); break;
                    case 7: LOADB(b0n0,b0n1,b0n2,b0n3,7,0); break;
                    case 8: LOADB(b0n0,b0n1,b0n2,b0n3,8,0); break;
                }
            }
            BURSTN(wc0, wc1, wc2, wc3, b10, b11, b12, b13, 4);   // half1
            wc0 = wn0; wc1 = wn1; wc2 = wn2; wc3 = wn3;
            b00 = b0n0; b01 = b0n1; b02 = b0n2; b03 = b0n3;
        }

        asm volatile("s_waitcnt vmcnt(0) lgkmcnt(0)" ::: "memory");
        __builtin_amdgcn_s_barrier();
        cur ^= 1;
    }

    // ---- epilogue: scale, per-wave LDS transpose, coalesced dwordx4 stores ----
    float dspb = dsp[b];
    float spn[2][4];
#pragma unroll
    for (int half = 0; half < 2; half++) {
        int hout = h0 + rpair * 2 + half;
#pragma unroll
        for (int nn = 0; nn < 4; nn++)
            spn[half][nn] = sp[b * SPP + hout * 64 + nn * 16 + lcol] * dspb;
    }

    float* ep = &lds.ep[w][0];
#pragma unroll
    for (int half = 0; half < 2; half++) {
        int hout = h0 + rpair * 2 + half;
#pragma unroll
        for (int ch = 0; ch < 2; ch++) {          // 2 chunks of 32 co
#pragma unroll
            for (int mm = 0; mm < 2; mm++) {
#pragma unroll
                for (int r2 = 0; r2 < 4; r2++) {
                    int lr = mm * 16 + kg * 4 + r2;
                    float dm = demod_l[cpair * 64 + ch * 32 + lr] * CONV_SCALE;
#pragma unroll
                    for (int nn = 0; nn < 4; nn++)
                        ep[lr * 68 + nn * 16 + lcol] =
                            acc[ch * 2 + mm][half * 4 + nn][r2] * dm * spn[half][nn];
                }
            }
#pragma unroll
            for (int i = 0; i < 8; i++) {
                int lr = i * 4 + kg;
                f32x4 v = *(const f32x4*)(ep + lr * 68 + lcol * 4);
                int co_g = coh * 128 + cpair * 64 + ch * 32 + lr;
                *(f32x4*)&out[((size_t)(b * 256 + co_g)) * SPP + hout * 64 + lcol * 4] = v;
            }
        }
    }
}

// ---------------- fallback-path kernels (round-1 known-good) --------------

__global__ void k_wsq(const float* __restrict__ weight, float* __restrict__ wsq,
                      unsigned* __restrict__ zero) {
    int co = blockIdx.x, ci = threadIdx.x;
    if (co == 0) zero[ci] = 0u;
    const float* wp = weight + (co * CIN + ci) * 9;
    float s = 0.f;
#pragma unroll
    for (int t = 0; t < 9; t++) { float v = wp[t]; s += v * v; }
    wsq[co * CIN + ci] = s;
}

__global__ void k_style_fb(const float* __restrict__ style_in,
                           const float* __restrict__ mod_w,
                           const float* __restrict__ mod_b,
                           const float* __restrict__ wsq,
                           float* __restrict__ style,
                           float* __restrict__ demod) {
    __shared__ float s_in[SDIM];
    __shared__ float s2[CIN];
    int b = blockIdx.x, t = threadIdx.x;
    s_in[t] = style_in[b * 512 + t];
    __syncthreads();
    const float* mw = mod_w + t * SDIM;
    float acc = 0.f;
    for (int k = 0; k < SDIM; k++) acc += s_in[k] * mw[k];
    float st = acc * LIN_SCALE + mod_b[t];
    style[b * CIN + t] = st;
    s2[t] = st * st;
    __syncthreads();
    const float* wq = wsq + t * CIN;
    float d = 0.f;
    for (int ci = 0; ci < CIN; ci++) d += wq[ci] * s2[ci];
    demod[b * COUT + t] = rsqrtf(CONV_SCALE * CONV_SCALE * d + EPS);
}

__global__ void k_spatial(const float* __restrict__ style_in,
                          const float* __restrict__ sp_w,
                          const float* __restrict__ sp_b,
                          float* __restrict__ sp,
                          float* __restrict__ dsp) {
    __shared__ float s_in[SDIM];
    __shared__ float red[256];
    int b = blockIdx.x, t = threadIdx.x;
    s_in[t] = style_in[b * 512 + 256 + t];
    __syncthreads();
    float ss = 0.f;
    for (int i = 0; i < 16; i++) {
        int p = i * 256 + t;
        const float* wr = sp_w + p * SDIM;
        float acc = 0.f;
        for (int k = 0; k < SDIM; k++) acc += s_in[k] * wr[k];
        float v = acc * LIN_SCALE + sp_b[p];
        sp[b * SPP + p] = v;
        ss += v * v;
    }
    red[t] = ss; __syncthreads();
    for (int o = 128; o > 0; o >>= 1) { if (t < o) red[t] += red[t + o]; __syncthreads(); }
    if (t == 0) dsp[b] = sqrtf((float)SPP / red[0] + EPS);
}

#define COTILE 16
#define TS 32
#define HALO 34
#define XS 36

__global__ __launch_bounds__(256) void k_conv_f32(
    const float* __restrict__ x, const float* __restrict__ weight,
    const float* __restrict__ style, const float* __restrict__ demod,
    const float* __restrict__ sp, const float* __restrict__ dsp,
    float* __restrict__ out) {
    __shared__ float xt[HALO * XS];
    __shared__ float wl[COTILE * 12];
    __shared__ float dml[COTILE];

    int bid = blockIdx.x;
    int tile = bid & 3;
    int cot = (bid >> 2) & 15;
    int b = bid >> 6;
    int h0 = (tile >> 1) * TS, w0 = (tile & 1) * TS;
    int t = threadIdx.x;
    int r = t >> 3;
    int cb = (t & 7) * 4;

    if (t < COTILE) dml[t] = demod[b * COUT + cot * COTILE + t];

    float acc[COTILE][4];
#pragma unroll
    for (int co = 0; co < COTILE; co++)
#pragma unroll
        for (int c = 0; c < 4; c++) acc[co][c] = 0.f;

    const float* xb = x + (size_t)b * CIN * SPP;
    const float* stb = style + b * CIN;

    for (int ci = 0; ci < CIN; ci++) {
        __syncthreads();
        const float* xc = xb + ci * SPP;
        for (int idx = t; idx < HALO * HALO; idx += 256) {
            int i = idx / HALO, j = idx - i * HALO;
            int h = h0 + i - 1, wv2 = w0 + j - 1;
            float v = 0.f;
            if ((unsigned)h < SPD && (unsigned)wv2 < SPD) v = xc[h * SPD + wv2];
            xt[i * XS + j] = v;
        }
        if (t < COTILE * 9) {
            int co = t / 9, tap = t - co * 9;
            float wv = weight[((cot * COTILE + co) * CIN + ci) * 9 + tap];
            wl[co * 12 + tap] = wv * (CONV_SCALE * stb[ci]) * dml[co];
        }
        __syncthreads();

        float xv[3][6];
#pragma unroll
        for (int dh = 0; dh < 3; dh++)
#pragma unroll
            for (int jj = 0; jj < 6; jj++)
                xv[dh][jj] = xt[(r + dh) * XS + cb + jj];

#pragma unroll
        for (int co = 0; co < COTILE; co++) {
            float w9[9];
#pragma unroll
            for (int q = 0; q < 9; q++) w9[q] = wl[co * 12 + q];
#pragma unroll
            for (int c = 0; c < 4; c++) {
                float a = acc[co][c];
#pragma unroll
                for (int dh = 0; dh < 3; dh++)
#pragma unroll
                    for (int dw = 0; dw < 3; dw++)
                        a += w9[dh * 3 + dw] * xv[dh][c + dw];
                acc[co][c] = a;
            }
        }
    }

    float dspb = dsp[b];
    int hh = h0 + r, ww = w0 + cb;
    const float* spb = sp + b * SPP + hh * SPD + ww;
    float m[4];
#pragma unroll
    for (int c = 0; c < 4; c++) m[c] = spb[c] * dspb;
#pragma unroll
    for (int co = 0; co < COTILE; co++) {
        float4 v = make_float4(acc[co][0] * m[0], acc[co][1] * m[1],
                               acc[co][2] * m[2], acc[co][3] * m[3]);
        *(float4*)&out[(size_t)((b * COUT + cot * COTILE + co) * SPP) + hh * SPD + ww] = v;
    }
}

// ---------------- launcher ----------------

extern "C" void kernel_launch(void* const* d_in, const int* in_sizes, int n_in,
                              void* d_out, int out_size, void* d_ws, size_t ws_size,
                              hipStream_t stream) {
    const float* x        = (const float*)d_in[0];
    const float* style_in = (const float*)d_in[1];
    const float* weight   = (const float*)d_in[2];
    const float* mod_w    = (const float*)d_in[3];
    const float* mod_b    = (const float*)d_in[4];
    const float* sp_w     = (const float*)d_in[5];
    const float* sp_b     = (const float*)d_in[6];
    float* out = (float*)d_out;
    char* wsb = (char*)d_ws;

    float* style = (float*)(wsb + WSB_STYLE);
    float* demod = (float*)(wsb + WSB_DEMOD);
    float* wsq   = (float*)(wsb + WSB_WSQ);
    float* sp    = (float*)(wsb + WSB_SP);
    float* dsp   = (float*)(wsb + WSB_DSP);
    float* ssqp  = (float*)(wsb + WSB_SSQP);
    unsigned short* wt4 = (unsigned short*)(wsb + WSB_WT2);
    unsigned short* xst = (unsigned short*)(wsb + WSB_XST);

    if (ws_size >= WS_NEED) {
        hipLaunchKernelGGL(k_prepA, dim3(2848), dim3(256), 0, stream,
                           weight, style_in, sp_w, sp_b, mod_w, mod_b,
                           wsq, wt4, sp, ssqp, style,
                           (unsigned*)(wsb + WSB_ZERO));
        hipLaunchKernelGGL(k_xt, dim3(2048), dim3(256), 0, stream, x, style, xst);
        hipLaunchKernelGGL(k_prepB, dim3(33), dim3(256), 0, stream,
                           wsq, ssqp, style, demod, dsp);
        hipLaunchKernelGGL(k_conv_mfma, dim3(1024), dim3(256), 0, stream,
                           xst, wt4, demod, sp, dsp,
                           (const unsigned short*)(wsb + WSB_ZERO), out);
    } else {
        hipLaunchKernelGGL(k_wsq, dim3(COUT), dim3(CIN), 0, stream,
                           weight, wsq, (unsigned*)(wsb + WSB_ZERO));
        hipLaunchKernelGGL(k_style_fb, dim3(BB), dim3(256), 0, stream,
                           style_in, mod_w, mod_b, wsq, style, demod);
        hipLaunchKernelGGL(k_spatial, dim3(BB), dim3(256), 0, stream,
                           style_in, sp_w, sp_b, sp, dsp);
        hipLaunchKernelGGL(k_conv_f32, dim3(2048), dim3(256), 0, stream,
                           x, weight, style, demod, sp, dsp, out);
    }
}

// Round 20
// 208.672 us; speedup vs baseline: 5.9734x; 1.0082x over previous
//
#include <hip/hip_runtime.h>
#include <math.h>

typedef short short8 __attribute__((ext_vector_type(8)));
typedef float f32x4 __attribute__((ext_vector_type(4)));

#define BB 32
#define CIN 256
#define COUT 256
#define SPD 64
#define SPP 4096
#define SDIM 256

constexpr float LIN_SCALE  = 0.0625f;                 // 1/sqrt(256)
constexpr float CONV_SCALE = 0.020833333333333332f;   // 1/sqrt(2304)
constexpr float EPS = 1e-6f;

// ---- ws byte-offset layout ----
#define WSB_STYLE   0ULL
#define WSB_DEMOD   32768ULL
#define WSB_WSQ     65536ULL
#define WSB_SP      327680ULL
#define WSB_DSP     851968ULL
#define WSB_ZERO    852096ULL      // 1 KiB of zeros
#define WSB_WT2     860160ULL      // 1,179,648 B bf16 weights [kc][tap][cog][lane][8]
#define WSB_SSQP    2039808ULL     // 32,768 B ssq partials [256][32] f32
#define WSB_XST     2097152ULL     // 67,108,864 B bf16 xs_t [b][p][ci]
#define WS_NEED     (WSB_XST + 67108864ULL)

__device__ inline unsigned short f2bf(float f) {
    unsigned u = __builtin_bit_cast(unsigned, f);
    u = (u + 0x7fffu + ((u >> 16) & 1u)) >> 16;   // RNE
    return (unsigned short)u;
}

// async global->LDS DMA, 16B per lane; LDS dest = wave-uniform base + lane*16
__device__ inline void dma16(const void* g, void* l) {
    __builtin_amdgcn_global_load_lds(
        (const __attribute__((address_space(1))) unsigned int*)g,
        (__attribute__((address_space(3))) unsigned int*)l, 16, 0, 0);
}

// ---------------- fused prep A: spatial2 + wt4 + wsq + style + zeropad ----
// grid 2848: [0,256) spatial2 | [256,2560) wt4 | [2560,2816) wsq(+zero)
//            | [2816,2848) style (b = bid-2816)
__global__ __launch_bounds__(256) void k_prepA(
    const float* __restrict__ weight,
    const float* __restrict__ style_in,
    const float* __restrict__ sp_w,
    const float* __restrict__ sp_b,
    const float* __restrict__ mod_w,
    const float* __restrict__ mod_b,
    float* __restrict__ wsq,
    unsigned short* __restrict__ wt4,
    float* __restrict__ sp,
    float* __restrict__ ssq_part,
    float* __restrict__ style,
    unsigned* __restrict__ zero)
{
    __shared__ float s_in[32][257];
    __shared__ float sred[256];
    int bid = blockIdx.x, t = threadIdx.x;

    if (bid < 256) {
        // ---- spatial map ----
        int p0 = bid * 16;
        for (int idx = t; idx < 8192; idx += 256) {
            int b = idx >> 8, k = idx & 255;
            s_in[b][k] = style_in[b * 512 + 256 + k];
        }
        __syncthreads();
        int b = t & 31, pl = t >> 5;
        float ss = 0.f;
#pragma unroll
        for (int half = 0; half < 2; half++) {
            int p = p0 + half * 8 + pl;
            const float* wr = sp_w + (size_t)p * 256;
            float a = 0.f;
            for (int k = 0; k < 256; k++) a += s_in[b][k] * wr[k];
            float v = a * LIN_SCALE + sp_b[p];
            sp[b * SPP + p] = v;
            ss += v * v;
        }
        sred[t] = ss;
        __syncthreads();
        if (t < 32) {
            float s = 0.f;
#pragma unroll
            for (int r = 0; r < 8; r++) s += sred[r * 32 + t];
            ssq_part[bid * 32 + t] = s;
        }
    } else if (bid < 2560) {
        // ---- wt4 repack: [kc][tap][cog][lane][8] bf16 ----
        int idx = (bid - 256) * 256 + t;
        int e    = idx & 7;
        int r1   = idx >> 3;
        int lane = r1 & 63;
        int r2   = r1 >> 6;
        int cog  = r2 & 15;
        int r3   = r2 >> 4;       // 0..71
        int tap  = r3 % 9;
        int kc   = r3 / 9;
        int co = cog * 16 + (lane & 15);
        int ci = kc * 32 + (lane >> 4) * 8 + e;
        wt4[idx] = f2bf(weight[(co * 256 + ci) * 9 + tap]);
    } else if (bid < 2816) {
        // ---- wsq (+ zeropad by first block) ----
        int co = bid - 2560, ci = t;
        if (co == 0) zero[ci] = 0u;
        const float* wp = weight + (co * CIN + ci) * 9;
        float s = 0.f;
#pragma unroll
        for (int q = 0; q < 9; q++) { float v = wp[q]; s += v * v; }
        wsq[co * CIN + ci] = s;
    } else {
        // ---- style (EqualLinear), coalesced 4-lane rows ----
        int b = bid - 2816;
        float* s_lin = &s_in[0][0];       // reuse shared
        s_lin[t] = style_in[b * 512 + t];
        __syncthreads();
        int kq = t & 3, rr = t >> 2;
#pragma unroll
        for (int c = 0; c < 4; c++) {
            int ci = c * 64 + rr;
            const float4* wrow = (const float4*)(mod_w + (size_t)ci * 256 + kq * 64);
            float a = 0.f;
#pragma unroll
            for (int j = 0; j < 16; j++) {
                float4 wv = wrow[j];
                int kb = kq * 64 + j * 4;
                a += s_lin[kb] * wv.x + s_lin[kb + 1] * wv.y + s_lin[kb + 2] * wv.z + s_lin[kb + 3] * wv.w;
            }
            a += __shfl_xor(a, 1); a += __shfl_xor(a, 2);
            if (kq == 0) style[b * 256 + ci] = a * LIN_SCALE + mod_b[ci];
        }
    }
}

// ---------------- fused prep C: xt + demod + dsp --------------------------
// grid 2081: [0,2048) xt | [2048,2080) demod (b=bid-2048) | 2080 dsp.
// All three depend only on prepA outputs (style/wsq/ssqp) -> one launch.
__global__ __launch_bounds__(256) void k_xt2(
    const float* __restrict__ x,
    const float* __restrict__ style,
    const float* __restrict__ wsq,
    const float* __restrict__ ssq_part,
    unsigned short* __restrict__ xst,
    float* __restrict__ demod,
    float* __restrict__ dsp)
{
    __shared__ union {
        unsigned short tileb[64][74];   // xt transpose tile (9.5 KB)
        float s2[CIN];                  // demod path
    } sh;
    int bid = blockIdx.x, t = threadIdx.x;

    if (bid >= 2048) {
        if (bid == 2080) {
            // ---- dsp ----
            if (t < 32) {
                float s = 0.f;
                for (int i = 0; i < 256; i++) s += ssq_part[i * 32 + t];
                dsp[t] = sqrtf((float)SPP / s + EPS);
            }
            return;
        }
        // ---- demod ----
        int b = bid - 2048;
        float st = style[b * 256 + t];
        sh.s2[t] = st * st;
        __syncthreads();
        int kq = t & 3, rr = t >> 2;
#pragma unroll
        for (int c = 0; c < 4; c++) {
            int co = c * 64 + rr;
            const float4* wrow = (const float4*)(wsq + (size_t)co * 256 + kq * 64);
            float a = 0.f;
#pragma unroll
            for (int j = 0; j < 16; j++) {
                float4 wv = wrow[j];
                int kb = kq * 64 + j * 4;
                a += sh.s2[kb] * wv.x + sh.s2[kb + 1] * wv.y + sh.s2[kb + 2] * wv.z + sh.s2[kb + 3] * wv.w;
            }
            a += __shfl_xor(a, 1); a += __shfl_xor(a, 2);
            if (kq == 0) demod[b * 256 + co] = rsqrtf(CONV_SCALE * CONV_SCALE * a + EPS);
        }
        return;
    }

    // ---- xt: x [b][ci][p] fp32 -> xs_t[b][p][ci] bf16 * style[b][ci] ----
    int b  = (bid & 7) * 4 + ((bid >> 3) & 3);
    int p0 = (bid >> 5) * 64;
    int w = t >> 6, lane = t & 63;
    int pq = lane & 15, cg = lane >> 4;
    int lo2 = t & 15;

    for (int cc = 0; cc < 4; cc++) {
#pragma unroll
        for (int j = 0; j < 4; j++) {
            int ci_l = w * 16 + j * 4 + cg;
            int ci = cc * 64 + ci_l;
            float st = style[b * 256 + ci];
            float4 v = *(const float4*)(x + ((size_t)(b * 256 + ci)) * SPP + p0 + pq * 4);
            sh.tileb[pq * 4 + 0][ci_l] = f2bf(v.x * st);
            sh.tileb[pq * 4 + 1][ci_l] = f2bf(v.y * st);
            sh.tileb[pq * 4 + 2][ci_l] = f2bf(v.z * st);
            sh.tileb[pq * 4 + 3][ci_l] = f2bf(v.w * st);
        }
        __syncthreads();
        // uint2 stores: 16 threads/row, 4 rows/iter/wave -> 16 iters total
#pragma unroll
        for (int it = 0; it < 4; it++) {
            int r = it * 16 + (t >> 4);
            unsigned pk0 = (unsigned)sh.tileb[r][lo2 * 4]
                         | ((unsigned)sh.tileb[r][lo2 * 4 + 1] << 16);
            unsigned pk1 = (unsigned)sh.tileb[r][lo2 * 4 + 2]
                         | ((unsigned)sh.tileb[r][lo2 * 4 + 3] << 16);
            uint2 pv = make_uint2(pk0, pk1);
            *(uint2*)((unsigned*)xst + ((size_t)(b * SPP + p0 + r)) * 128 + cc * 32 + lo2 * 2) = pv;
        }
        __syncthreads();
    }
}

// ---------------- MFMA conv kernel (n=8, launch_bounds(256,2)) ------------
// grid 1024: bid -> [rq(4)][coh(1)][b_lo(2)][xcd(3)], b = xcd*4+b_lo,
// h0 = rq*4. block 256 = 4 waves: cpair=w&1 -> 64-co slab, rpair=w>>1 ->
// rows h0+rpair*2+{0,1}. Wave: 64 co x 128 p, 36 weight loads -> 288 MFMAs.
// NOTE (r18 lesson): unified VGPR/AGPR file -- acc[4][8] = 128 AGPRs counts
// against the per-wave budget. launch_bounds(256,3) caps at ~170 total ->
// the ~110 pipeline regs spill to scratch (2.7GB scratch writes, 7x slower).
// MUST stay at (256,2) = 256-reg cap. r17/r19 measured: 123us, MfmaUtil 57%.
__global__ __launch_bounds__(256, 2) void k_conv_mfma(
    const unsigned short* __restrict__ xst,
    const unsigned short* __restrict__ wt4,
    const float* __restrict__ demod,
    const float* __restrict__ sp,
    const float* __restrict__ dsp,
    const unsigned short* __restrict__ zeropad,
    float* __restrict__ out)
{
    __shared__ union {
        char stage[2][25344];      // 2 x 396 slots x 64B (1584 16B-units each)
        float ep[4][2176];         // 4 waves x 32 rows x 68 floats (34816 B)
    } lds;
    __shared__ float demod_l[128];

    int bid = blockIdx.x;
    int xcd  = bid & 7;
    int b_lo = (bid >> 3) & 3;
    int coh  = (bid >> 5) & 1;
    int rq   = bid >> 6;           // 0..15
    int b  = xcd * 4 + b_lo;
    int h0 = rq * 4;
    int t = threadIdx.x;
    int w = t >> 6, lane = t & 63;
    int cpair = w & 1, rpair = w >> 1;
    int cog0 = coh * 8 + cpair * 4;
    int lcol = lane & 15, kg = lane >> 4;

    if (t < 128) demod_l[t] = demod[b * 256 + coh * 128 + t];

    const unsigned short* xb = xst + (size_t)b * SPP * 256;

    // per-thread DMA source pointers (kc advances source by 32 elements)
    const unsigned short* sbase[7];
#pragma unroll
    for (int it = 0; it < 7; it++) {
        int idx16 = t + it * 256;
        const unsigned short* s = zeropad;
        if (idx16 < 1584) {
            int slot = idx16 >> 2, j = idx16 & 3;
            int row = slot / 66, col = slot - row * 66;   // row 0..5
            int g = j ^ ((slot >> 1) & 3);     // inverse swizzle on source
            int gh = h0 + row - 1, gw = col - 1;
            if ((unsigned)gh < 64u && (unsigned)gw < 64u)
                s = xb + ((size_t)(gh * 64 + gw)) * 256 + g * 8;
        }
        sbase[it] = s;
    }

#define STAGE_DMA(BUF, KC) { _Pragma("unroll") \
    for (int it = 0; it < 6; it++) \
        dma16(sbase[it] + (KC) * 32, &lds.stage[BUF][0] + (t + it * 256) * 16); \
    if (t < 48) dma16(sbase[6] + (KC) * 32, &lds.stage[BUF][0] + (t + 1536) * 16); }

    STAGE_DMA(0, 0);

    f32x4 acc[4][8];
#pragma unroll
    for (int m = 0; m < 4; m++)
#pragma unroll
        for (int n = 0; n < 8; n++) acc[m][n] = (f32x4){0.f, 0.f, 0.f, 0.f};

    asm volatile("s_waitcnt vmcnt(0) lgkmcnt(0)" ::: "memory");
    __builtin_amdgcn_s_barrier();

#define LOADW(a0,a1,a2,a3, TAP) { \
        const unsigned short* wp_ = wkc + (size_t)(((TAP) * 16 + cog0)) * 512 + lane * 8; \
        a0 = *(const short8*)(wp_); \
        a1 = *(const short8*)(wp_ + 512); \
        a2 = *(const short8*)(wp_ + 1024); \
        a3 = *(const short8*)(wp_ + 1536); }

#define LOADB(a0,a1,a2,a3, TAP, HALF) { \
        const int dh_ = (TAP) / 3, dw_ = (TAP) - 3 * (dh_); \
        int s0_ = (rpair * 2 + (HALF) + dh_) * 66 + dw_ + lcol; \
        int q_ = (s0_ >> 1) & 3; \
        const char* lbp_ = lb + s0_ * 64 + ((kg ^ q_) << 4); \
        a0 = *(const short8*)(lbp_); \
        a1 = *(const short8*)(lbp_ + 1024); \
        a2 = *(const short8*)(lbp_ + 2048); \
        a3 = *(const short8*)(lbp_ + 3072); }

#define BURSTN(w0_,w1_,w2_,w3_, x0_,x1_,x2_,x3_, NO) { \
        __builtin_amdgcn_s_setprio(1); \
        acc[0][NO+0] = __builtin_amdgcn_mfma_f32_16x16x32_bf16(w0_, x0_, acc[0][NO+0], 0, 0, 0); \
        acc[1][NO+0] = __builtin_amdgcn_mfma_f32_16x16x32_bf16(w1_, x0_, acc[1][NO+0], 0, 0, 0); \
        acc[2][NO+0] = __builtin_amdgcn_mfma_f32_16x16x32_bf16(w2_, x0_, acc[2][NO+0], 0, 0, 0); \
        acc[3][NO+0] = __builtin_amdgcn_mfma_f32_16x16x32_bf16(w3_, x0_, acc[3][NO+0], 0, 0, 0); \
        acc[0][NO+1] = __builtin_amdgcn_mfma_f32_16x16x32_bf16(w0_, x1_, acc[0][NO+1], 0, 0, 0); \
        acc[1][NO+1] = __builtin_amdgcn_mfma_f32_16x16x32_bf16(w1_, x1_, acc[1][NO+1], 0, 0, 0); \
        acc[2][NO+1] = __builtin_amdgcn_mfma_f32_16x16x32_bf16(w2_, x1_, acc[2][NO+1], 0, 0, 0); \
        acc[3][NO+1] = __builtin_amdgcn_mfma_f32_16x16x32_bf16(w3_, x1_, acc[3][NO+1], 0, 0, 0); \
        acc[0][NO+2] = __builtin_amdgcn_mfma_f32_16x16x32_bf16(w0_, x2_, acc[0][NO+2], 0, 0, 0); \
        acc[1][NO+2] = __builtin_amdgcn_mfma_f32_16x16x32_bf16(w1_, x2_, acc[1][NO+2], 0, 0, 0); \
        acc[2][NO+2] = __builtin_amdgcn_mfma_f32_16x16x32_bf16(w2_, x2_, acc[2][NO+2], 0, 0, 0); \
        acc[3][NO+2] = __builtin_amdgcn_mfma_f32_16x16x32_bf16(w3_, x2_, acc[3][NO+2], 0, 0, 0); \
        acc[0][NO+3] = __builtin_amdgcn_mfma_f32_16x16x32_bf16(w0_, x3_, acc[0][NO+3], 0, 0, 0); \
        acc[1][NO+3] = __builtin_amdgcn_mfma_f32_16x16x32_bf16(w1_, x3_, acc[1][NO+3], 0, 0, 0); \
        acc[2][NO+3] = __builtin_amdgcn_mfma_f32_16x16x32_bf16(w2_, x3_, acc[2][NO+3], 0, 0, 0); \
        acc[3][NO+3] = __builtin_amdgcn_mfma_f32_16x16x32_bf16(w3_, x3_, acc[3][NO+3], 0, 0, 0); \
        __builtin_amdgcn_s_setprio(0); }

    int cur = 0;
    for (int kc = 0; kc < 8; kc++) {
        const char* lb = &lds.stage[cur][0];
        const unsigned short* wkc = wt4 + (size_t)(kc * 9) * 8192;

        short8 wc0, wc1, wc2, wc3, wn0, wn1, wn2, wn3;
        short8 b00, b01, b02, b03, b0n0, b0n1, b0n2, b0n3;
        short8 b10, b11, b12, b13;
        // A(0), B(0,h0), A(1) issued FIRST (oldest in vmcnt queue), DMA after
        LOADW(wc0, wc1, wc2, wc3, 0);
        LOADB(b00, b01, b02, b03, 0, 0);
        LOADW(wn0, wn1, wn2, wn3, 1);
        if (kc < 7) STAGE_DMA(cur ^ 1, kc + 1);

#pragma unroll
        for (int tap = 0; tap < 9; tap++) {
            if (tap >= 1 && tap < 8) {
                switch (tap + 1) {   // A(tap+1); tap0's A(1) preloaded
                    case 2: LOADW(wn0,wn1,wn2,wn3,2); break;
                    case 3: LOADW(wn0,wn1,wn2,wn3,3); break;
                    case 4: LOADW(wn0,wn1,wn2,wn3,4); break;
                    case 5: LOADW(wn0,wn1,wn2,wn3,5); break;
                    case 6: LOADW(wn0,wn1,wn2,wn3,6); break;
                    case 7: LOADW(wn0,wn1,wn2,wn3,7); break;
                    case 8: LOADW(wn0,wn1,wn2,wn3,8); break;
                }
            }
            switch (tap) {           // B(tap, h1), consumed by BURST half1
                case 0: LOADB(b10,b11,b12,b13,0,1); break;
                case 1: LOADB(b10,b11,b12,b13,1,1); break;
                case 2: LOADB(b10,b11,b12,b13,2,1); break;
                case 3: LOADB(b10,b11,b12,b13,3,1); break;
                case 4: LOADB(b10,b11,b12,b13,4,1); break;
                case 5: LOADB(b10,b11,b12,b13,5,1); break;
                case 6: LOADB(b10,b11,b12,b13,6,1); break;
                case 7: LOADB(b10,b11,b12,b13,7,1); break;
                case 8: LOADB(b10,b11,b12,b13,8,1); break;
            }
            BURSTN(wc0, wc1, wc2, wc3, b00, b01, b02, b03, 0);   // half0
            if (tap < 8) {
                switch (tap + 1) {   // B(tap+1, h0)
                    case 1: LOADB(b0n0,b0n1,b0n2,b0n3,1,0); break;
                    case 2: LOADB(b0n0,b0n1,b0n2,b0n3,2,0); break;
                    case 3: LOADB(b0n0,b0n1,b0n2,b0n3,3,0); break;
                    case 4: LOADB(b0n0,b0n1,b0n2,b0n3,4,0); break;
                    case 5: LOADB(b0n0,b0n1,b0n2,b0n3,5,0); break;
                    case 6: LOADB(b0n0,b0n1,b0n2,b0n3,6,0); break;
                    case 7: LOADB(b0n0,b0n1,b0n2,b0n3,7,0); break;
                    case 8: LOADB(b0n0,b0n1,b0n2,b0n3,8,0); break;
                }
            }
            BURSTN(wc0, wc1, wc2, wc3, b10, b11, b12, b13, 4);   // half1
            wc0 = wn0; wc1 = wn1; wc2 = wn2; wc3 = wn3;
            b00 = b0n0; b01 = b0n1; b02 = b0n2; b03 = b0n3;
        }

        asm volatile("s_waitcnt vmcnt(0) lgkmcnt(0)" ::: "memory");
        __builtin_amdgcn_s_barrier();
        cur ^= 1;
    }

    // ---- epilogue: scale, per-wave LDS transpose, coalesced dwordx4 stores ----
    float dspb = dsp[b];
    float spn[2][4];
#pragma unroll
    for (int half = 0; half < 2; half++) {
        int hout = h0 + rpair * 2 + half;
#pragma unroll
        for (int nn = 0; nn < 4; nn++)
            spn[half][nn] = sp[b * SPP + hout * 64 + nn * 16 + lcol] * dspb;
    }

    float* ep = &lds.ep[w][0];
#pragma unroll
    for (int half = 0; half < 2; half++) {
        int hout = h0 + rpair * 2 + half;
#pragma unroll
        for (int ch = 0; ch < 2; ch++) {          // 2 chunks of 32 co
#pragma unroll
            for (int mm = 0; mm < 2; mm++) {
#pragma unroll
                for (int r2 = 0; r2 < 4; r2++) {
                    int lr = mm * 16 + kg * 4 + r2;
                    float dm = demod_l[cpair * 64 + ch * 32 + lr] * CONV_SCALE;
#pragma unroll
                    for (int nn = 0; nn < 4; nn++)
                        ep[lr * 68 + nn * 16 + lcol] =
                            acc[ch * 2 + mm][half * 4 + nn][r2] * dm * spn[half][nn];
                }
            }
#pragma unroll
            for (int i = 0; i < 8; i++) {
                int lr = i * 4 + kg;
                f32x4 v = *(const f32x4*)(ep + lr * 68 + lcol * 4);
                int co_g = coh * 128 + cpair * 64 + ch * 32 + lr;
                *(f32x4*)&out[((size_t)(b * 256 + co_g)) * SPP + hout * 64 + lcol * 4] = v;
            }
        }
    }
}

// ---------------- fallback-path kernels (round-1 known-good) --------------

__global__ void k_wsq(const float* __restrict__ weight, float* __restrict__ wsq,
                      unsigned* __restrict__ zero) {
    int co = blockIdx.x, ci = threadIdx.x;
    if (co == 0) zero[ci] = 0u;
    const float* wp = weight + (co * CIN + ci) * 9;
    float s = 0.f;
#pragma unroll
    for (int t = 0; t < 9; t++) { float v = wp[t]; s += v * v; }
    wsq[co * CIN + ci] = s;
}

__global__ void k_style_fb(const float* __restrict__ style_in,
                           const float* __restrict__ mod_w,
                           const float* __restrict__ mod_b,
                           const float* __restrict__ wsq,
                           float* __restrict__ style,
                           float* __restrict__ demod) {
    __shared__ float s_in[SDIM];
    __shared__ float s2[CIN];
    int b = blockIdx.x, t = threadIdx.x;
    s_in[t] = style_in[b * 512 + t];
    __syncthreads();
    const float* mw = mod_w + t * SDIM;
    float acc = 0.f;
    for (int k = 0; k < SDIM; k++) acc += s_in[k] * mw[k];
    float st = acc * LIN_SCALE + mod_b[t];
    style[b * CIN + t] = st;
    s2[t] = st * st;
    __syncthreads();
    const float* wq = wsq + t * CIN;
    float d = 0.f;
    for (int ci = 0; ci < CIN; ci++) d += wq[ci] * s2[ci];
    demod[b * COUT + t] = rsqrtf(CONV_SCALE * CONV_SCALE * d + EPS);
}

__global__ void k_spatial(const float* __restrict__ style_in,
                          const float* __restrict__ sp_w,
                          const float* __restrict__ sp_b,
                          float* __restrict__ sp,
                          float* __restrict__ dsp) {
    __shared__ float s_in[SDIM];
    __shared__ float red[256];
    int b = blockIdx.x, t = threadIdx.x;
    s_in[t] = style_in[b * 512 + 256 + t];
    __syncthreads();
    float ss = 0.f;
    for (int i = 0; i < 16; i++) {
        int p = i * 256 + t;
        const float* wr = sp_w + p * SDIM;
        float acc = 0.f;
        for (int k = 0; k < SDIM; k++) acc += s_in[k] * wr[k];
        float v = acc * LIN_SCALE + sp_b[p];
        sp[b * SPP + p] = v;
        ss += v * v;
    }
    red[t] = ss; __syncthreads();
    for (int o = 128; o > 0; o >>= 1) { if (t < o) red[t] += red[t + o]; __syncthreads(); }
    if (t == 0) dsp[b] = sqrtf((float)SPP / red[0] + EPS);
}

#define COTILE 16
#define TS 32
#define HALO 34
#define XS 36

__global__ __launch_bounds__(256) void k_conv_f32(
    const float* __restrict__ x, const float* __restrict__ weight,
    const float* __restrict__ style, const float* __restrict__ demod,
    const float* __restrict__ sp, const float* __restrict__ dsp,
    float* __restrict__ out) {
    __shared__ float xt[HALO * XS];
    __shared__ float wl[COTILE * 12];
    __shared__ float dml[COTILE];

    int bid = blockIdx.x;
    int tile = bid & 3;
    int cot = (bid >> 2) & 15;
    int b = bid >> 6;
    int h0 = (tile >> 1) * TS, w0 = (tile & 1) * TS;
    int t = threadIdx.x;
    int r = t >> 3;
    int cb = (t & 7) * 4;

    if (t < COTILE) dml[t] = demod[b * COUT + cot * COTILE + t];

    float acc[COTILE][4];
#pragma unroll
    for (int co = 0; co < COTILE; co++)
#pragma unroll
        for (int c = 0; c < 4; c++) acc[co][c] = 0.f;

    const float* xb = x + (size_t)b * CIN * SPP;
    const float* stb = style + b * CIN;

    for (int ci = 0; ci < CIN; ci++) {
        __syncthreads();
        const float* xc = xb + ci * SPP;
        for (int idx = t; idx < HALO * HALO; idx += 256) {
            int i = idx / HALO, j = idx - i * HALO;
            int h = h0 + i - 1, wv2 = w0 + j - 1;
            float v = 0.f;
            if ((unsigned)h < SPD && (unsigned)wv2 < SPD) v = xc[h * SPD + wv2];
            xt[i * XS + j] = v;
        }
        if (t < COTILE * 9) {
            int co = t / 9, tap = t - co * 9;
            float wv = weight[((cot * COTILE + co) * CIN + ci) * 9 + tap];
            wl[co * 12 + tap] = wv * (CONV_SCALE * stb[ci]) * dml[co];
        }
        __syncthreads();

        float xv[3][6];
#pragma unroll
        for (int dh = 0; dh < 3; dh++)
#pragma unroll
            for (int jj = 0; jj < 6; jj++)
                xv[dh][jj] = xt[(r + dh) * XS + cb + jj];

#pragma unroll
        for (int co = 0; co < COTILE; co++) {
            float w9[9];
#pragma unroll
            for (int q = 0; q < 9; q++) w9[q] = wl[co * 12 + q];
#pragma unroll
            for (int c = 0; c < 4; c++) {
                float a = acc[co][c];
#pragma unroll
                for (int dh = 0; dh < 3; dh++)
#pragma unroll
                    for (int dw = 0; dw < 3; dw++)
                        a += w9[dh * 3 + dw] * xv[dh][c + dw];
                acc[co][c] = a;
            }
        }
    }

    float dspb = dsp[b];
    int hh = h0 + r, ww = w0 + cb;
    const float* spb = sp + b * SPP + hh * SPD + ww;
    float m[4];
#pragma unroll
    for (int c = 0; c < 4; c++) m[c] = spb[c] * dspb;
#pragma unroll
    for (int co = 0; co < COTILE; co++) {
        float4 v = make_float4(acc[co][0] * m[0], acc[co][1] * m[1],
                               acc[co][2] * m[2], acc[co][3] * m[3]);
        *(float4*)&out[(size_t)((b * COUT + cot * COTILE + co) * SPP) + hh * SPD + ww] = v;
    }
}

// ---------------- launcher ----------------

extern "C" void kernel_launch(void* const* d_in, const int* in_sizes, int n_in,
                              void* d_out, int out_size, void* d_ws, size_t ws_size,
                              hipStream_t stream) {
    const float* x        = (const float*)d_in[0];
    const float* style_in = (const float*)d_in[1];
    const float* weight   = (const float*)d_in[2];
    const float* mod_w    = (const float*)d_in[3];
    const float* mod_b    = (const float*)d_in[4];
    const float* sp_w     = (const float*)d_in[5];
    const float* sp_b     = (const float*)d_in[6];
    float* out = (float*)d_out;
    char* wsb = (char*)d_ws;

    float* style = (float*)(wsb + WSB_STYLE);
    float* demod = (float*)(wsb + WSB_DEMOD);
    float* wsq   = (float*)(wsb + WSB_WSQ);
    float* sp    = (float*)(wsb + WSB_SP);
    float* dsp   = (float*)(wsb + WSB_DSP);
    float* ssqp  = (float*)(wsb + WSB_SSQP);
    unsigned short* wt4 = (unsigned short*)(wsb + WSB_WT2);
    unsigned short* xst = (unsigned short*)(wsb + WSB_XST);

    if (ws_size >= WS_NEED) {
        hipLaunchKernelGGL(k_prepA, dim3(2848), dim3(256), 0, stream,
                           weight, style_in, sp_w, sp_b, mod_w, mod_b,
                           wsq, wt4, sp, ssqp, style,
                           (unsigned*)(wsb + WSB_ZERO));
        hipLaunchKernelGGL(k_xt2, dim3(2081), dim3(256), 0, stream,
                           x, style, wsq, ssqp, xst, demod, dsp);
        hipLaunchKernelGGL(k_conv_mfma, dim3(1024), dim3(256), 0, stream,
                           xst, wt4, demod, sp, dsp,
                           (const unsigned short*)(wsb + WSB_ZERO), out);
    } else {
        hipLaunchKernelGGL(k_wsq, dim3(COUT), dim3(CIN), 0, stream,
                           weight, wsq, (unsigned*)(wsb + WSB_ZERO));
        hipLaunchKernelGGL(k_style_fb, dim3(BB), dim3(256), 0, stream,
                           style_in, mod_w, mod_b, wsq, style, demod);
        hipLaunchKernelGGL(k_spatial, dim3(BB), dim3(256), 0, stream,
                           style_in, sp_w, sp_b, sp, dsp);
        hipLaunchKernelGGL(k_conv_f32, dim3(2048), dim3(256), 0, stream,
                           x, weight, style, demod, sp, dsp, out);
    }
}